// Round 11
// baseline (435.589 us; speedup 1.0000x reference)
//
#include <hip/hip_runtime.h>
#include <hip/hip_bf16.h>
#include <math.h>

#define Nn   1024
#define Cn   192
#define KEPT 256
#define COMP 512
#define UT   128
#define KT   64
#define MARGIN 4e-4f
#define WCAP 512

typedef __attribute__((ext_vector_type(8))) _Float16 half8v;
typedef __attribute__((ext_vector_type(4))) float f32x4;

__device__ __forceinline__ unsigned encf(float f) {
    unsigned u = __float_as_uint(f);
    return (u & 0x80000000u) ? ~u : (u | 0x80000000u);
}
// pack 4 floats into one u64 of 4 fp16 (RNE)
__device__ __forceinline__ unsigned long long cvt4(float m0, float m1, float m2, float m3) {
    unsigned short h0 = __builtin_bit_cast(unsigned short, (_Float16)m0);
    unsigned short h1 = __builtin_bit_cast(unsigned short, (_Float16)m1);
    unsigned short h2 = __builtin_bit_cast(unsigned short, (_Float16)m2);
    unsigned short h3 = __builtin_bit_cast(unsigned short, (_Float16)m3);
    return (unsigned long long)h0 | ((unsigned long long)h1 << 16)
         | ((unsigned long long)h2 << 32) | ((unsigned long long)h3 << 48);
}

// ---------------- Kernel A: w = 1/sumsq, rsw = rsqrt(sumsq) ----------------
__global__ __launch_bounds__(768) void norm_kernel(const float* __restrict__ x,
                                                   float* __restrict__ w,
                                                   float* __restrict__ rsw) {
    __shared__ float4 red[16][48];
    int b = blockIdx.x, t = threadIdx.x;
    int c4 = t % 48, ng = t / 48;
    const float* xb = x + (size_t)b * Nn * Cn;
    float4 s = make_float4(0.f, 0.f, 0.f, 0.f);
    for (int i = 0; i < 64; ++i) {
        float4 v = *reinterpret_cast<const float4*>(
            xb + (size_t)(ng * 64 + i) * Cn + c4 * 4);
        s.x += v.x * v.x; s.y += v.y * v.y; s.z += v.z * v.z; s.w += v.w * v.w;
    }
    red[ng][c4] = s;
    __syncthreads();
    if (t < 48) {
        float4 a = make_float4(0.f, 0.f, 0.f, 0.f);
        #pragma unroll
        for (int g = 0; g < 16; ++g) {
            float4 v = red[g][t];
            a.x += v.x; a.y += v.y; a.z += v.z; a.w += v.w;
        }
        float4 wv = make_float4(1.0f / a.x, 1.0f / a.y, 1.0f / a.z, 1.0f / a.w);
        float4 rv = make_float4(rsqrtf(a.x), rsqrtf(a.y), rsqrtf(a.z), rsqrtf(a.w));
        *reinterpret_cast<float4*>(w   + (size_t)b * Cn + t * 4) = wv;
        *reinterpret_cast<float4*>(rsw + (size_t)b * Cn + t * 4) = rv;
    }
}

// ======= Kernel B: one block per b — fp16 MFMA sim (4 u-chunks) + gather merge =======
// LDS ~77 KB -> 2 blocks/CU (VGPR pinned to 128 via launch_bounds).
__global__ __launch_bounds__(512, 4) void simmerge_kernel(const float* __restrict__ x,
                                                          const float* __restrict__ w,
                                                          const float* __restrict__ rsw,
                                                          float* __restrict__ out) {
    __shared__ __align__(16) unsigned short su_h[UT * Cn];    // 49152 B
    __shared__ __align__(16) unsigned short sk_h[KT * Cn];    // 24576 B (merge scratch overlay)
    __shared__ float rl[Cn];                                  //   768 B
    __shared__ float wl[Cn];                                  //   768 B
    __shared__ float rowthr[UT];                              //   512 B
    __shared__ unsigned long long best[UT];                   //  1024 B
    __shared__ unsigned short wlist[WCAP];                    //  1024 B
    __shared__ int nc;                                        //     4 B
    __shared__ unsigned short dstl[COMP];                     //  1024 B  (k < 256 fits u16)

    const int b = blockIdx.x;
    const int t = threadIdx.x;
    const float* xb = x + (size_t)b * Nn * Cn;

    if (t < Cn) { rl[t] = rsw[b * Cn + t]; wl[t] = w[b * Cn + t]; }
    __syncthreads();

    const int wv   = t >> 6;
    const int ln   = t & 63;
    const int l15  = ln & 15;
    const int hi2  = ln >> 4;
    const int akey = (l15 & 7) << 4;
    const int abase = (wv * 16 + l15) * 384;
    int bbase[4];
    #pragma unroll
    for (int j = 0; j < 4; ++j) bbase[j] = (j * 16 + l15) * 384;

    // ---------------- Phase 1: sim + argmax per 128-u chunk ----------------
    for (int uc = 0; uc < 4; ++uc) {
        const int u0 = uc * UT;
        __syncthreads();   // prior-chunk LDS reads done
        if (t < UT) { rowthr[t] = INFINITY; best[t] = 0ull; }
        if (t == 0) nc = 0;
        __syncthreads();

        // stage su (128 unimp rows) as fp16, swizzled
        #pragma unroll
        for (int i = 0; i < 12; ++i) {
            int idx = t + 512 * i;
            int r = idx / 48, c4 = idx % 48;
            float4 v = *reinterpret_cast<const float4*>(
                xb + (size_t)(KEPT + u0 + r) * Cn + c4 * 4);
            unsigned long long h = cvt4(v.x * rl[c4 * 4 + 0], v.y * rl[c4 * 4 + 1],
                                        v.z * rl[c4 * 4 + 2], v.w * rl[c4 * 4 + 3]);
            int byte = r * 384 + ((c4 * 8) ^ ((r & 7) << 4));
            *reinterpret_cast<unsigned long long*>(reinterpret_cast<char*>(su_h) + byte) = h;
        }

        float4 pf[6];
        #pragma unroll
        for (int i = 0; i < 6; ++i) {
            int idx = t + 512 * i;
            int r = idx / 48, c4 = idx % 48;
            pf[i] = *reinterpret_cast<const float4*>(xb + (size_t)r * Cn + c4 * 4);
        }

        f32x4 acc[4][4];
        #pragma unroll
        for (int kt = 0; kt < 4; ++kt)
            #pragma unroll
            for (int j = 0; j < 4; ++j) acc[kt][j] = (f32x4)0.f;

        #pragma unroll
        for (int kt = 0; kt < 4; ++kt) {
            __syncthreads();
            #pragma unroll
            for (int i = 0; i < 6; ++i) {
                int idx = t + 512 * i;
                int r = idx / 48, c4 = idx % 48;
                unsigned long long h = cvt4(pf[i].x * rl[c4 * 4 + 0], pf[i].y * rl[c4 * 4 + 1],
                                            pf[i].z * rl[c4 * 4 + 2], pf[i].w * rl[c4 * 4 + 3]);
                int byte = r * 384 + ((c4 * 8) ^ ((r & 7) << 4));
                *reinterpret_cast<unsigned long long*>(reinterpret_cast<char*>(sk_h) + byte) = h;
            }
            __syncthreads();
            if (kt < 3) {
                #pragma unroll
                for (int i = 0; i < 6; ++i) {
                    int idx = t + 512 * i;
                    int r = idx / 48, c4 = idx % 48;
                    pf[i] = *reinterpret_cast<const float4*>(
                        xb + (size_t)((kt + 1) * KT + r) * Cn + c4 * 4);
                }
            }

            #pragma unroll
            for (int ks = 0; ks < 6; ++ks) {
                int koff = (ks * 64 + hi2 * 16) ^ akey;
                half8v ah = *reinterpret_cast<const half8v*>(
                    reinterpret_cast<const char*>(su_h) + abase + koff);
                #pragma unroll
                for (int j = 0; j < 4; ++j) {
                    half8v bh = *reinterpret_cast<const half8v*>(
                        reinterpret_cast<const char*>(sk_h) + bbase[j] + koff);
                    acc[kt][j] = __builtin_amdgcn_mfma_f32_16x16x32_f16(ah, bh, acc[kt][j], 0, 0, 0);
                }
            }
        }

        // ---- top-2 (value, argmax-with-lowest-k, 2nd value) per row ----
        float v1[4], v2[4];
        int   i1[4];
        #pragma unroll
        for (int r = 0; r < 4; ++r) { v1[r] = -INFINITY; v2[r] = -INFINITY; i1[r] = 1; }

        #pragma unroll
        for (int kt = 0; kt < 4; ++kt)
            #pragma unroll
            for (int j = 0; j < 4; ++j) {
                int k = kt * KT + j * 16 + l15;
                #pragma unroll
                for (int r = 0; r < 4; ++r) {
                    float v = acc[kt][j][r];
                    if (k != 0) {
                        if (v > v1[r]) { v2[r] = v1[r]; v1[r] = v; i1[r] = k; }
                        else if (v > v2[r]) v2[r] = v;
                    }
                }
            }

        #pragma unroll
        for (int r = 0; r < 4; ++r) {
            #pragma unroll
            for (int off = 1; off < 16; off <<= 1) {
                float ov1 = __shfl_xor(v1[r], off);
                int   oi1 = __shfl_xor(i1[r], off);
                float ov2 = __shfl_xor(v2[r], off);
                if (ov1 > v1[r] || (ov1 == v1[r] && oi1 < i1[r])) {
                    v2[r] = fmaxf(v1[r], ov2);
                    v1[r] = ov1; i1[r] = oi1;
                } else {
                    v2[r] = fmaxf(v2[r], ov1);
                }
            }
        }

        if (l15 == 0) {
            #pragma unroll
            for (int r = 0; r < 4; ++r) {
                int ur = wv * 16 + hi2 * 4 + r;
                if (v1[r] - v2[r] > MARGIN) dstl[u0 + ur] = (unsigned short)i1[r];
                else rowthr[ur] = v1[r] - MARGIN;
            }
        }
        __syncthreads();

        // ---- candidate push for flagged rows ----
        #pragma unroll
        for (int kt = 0; kt < 4; ++kt)
            #pragma unroll
            for (int j = 0; j < 4; ++j) {
                int k = kt * KT + j * 16 + l15;
                if (k == 0) continue;
                #pragma unroll
                for (int r = 0; r < 4; ++r) {
                    int ur = wv * 16 + hi2 * 4 + r;
                    if (acc[kt][j][r] >= rowthr[ur]) {
                        int pos = atomicAdd(&nc, 1);
                        if (pos < WCAP)
                            wlist[pos] = (unsigned short)((ur << 8) | k);
                    }
                }
            }
        __syncthreads();

        // ---- wave-parallel exact fp32 rescue ----
        int n = nc < WCAP ? nc : WCAP;
        for (int ci = wv; ci < n; ci += 8) {
            unsigned item = wlist[ci];
            int ur = item >> 8, k = item & 255;
            const float* xu = xb + (size_t)(KEPT + u0 + ur) * Cn;
            const float* xk = xb + (size_t)k * Cn;
            float p = 0.f;
            if (ln < 48) {
                float4 a  = *reinterpret_cast<const float4*>(xu + ln * 4);
                float4 b4 = *reinterpret_cast<const float4*>(xk + ln * 4);
                p = a.x * b4.x * wl[ln * 4 + 0] + a.y * b4.y * wl[ln * 4 + 1]
                  + a.z * b4.z * wl[ln * 4 + 2] + a.w * b4.w * wl[ln * 4 + 3];
            }
            #pragma unroll
            for (int off = 32; off >= 1; off >>= 1) p += __shfl_xor(p, off);
            if (ln == 0) {
                unsigned long long e = ((unsigned long long)encf(p) << 32)
                                     | (unsigned long long)(0xFFFFFFFFu - (unsigned)k);
                atomicMax(&best[ur], e);
            }
        }
        __syncthreads();

        if (t < UT && rowthr[t] < 3.0e38f) {
            unsigned k = 0xFFFFFFFFu - (unsigned)(best[t] & 0xFFFFFFFFull);
            dstl[u0 + t] = (unsigned short)k;
        }
    }
    __syncthreads();

    // ---------------- Phase 2: counting-sort gather merge (scratch overlays sk_h) ----------------
    int* cnt  = reinterpret_cast<int*>(sk_h);          // 1024 B
    int* offp = cnt + KEPT;                            // 1024 B
    int* fill = offp + KEPT;                           // 1024 B
    unsigned short* list = reinterpret_cast<unsigned short*>(fill + KEPT);  // 1024 B

    if (t < KEPT) { cnt[t] = 0; fill[t] = 0; }
    __syncthreads();
    atomicAdd(&cnt[dstl[t]], 1);
    __syncthreads();

    if (t < KEPT) offp[t] = cnt[t];
    __syncthreads();
    #pragma unroll
    for (int d = 1; d < KEPT; d <<= 1) {     // Hillis-Steele inclusive scan
        int v = 0;
        if (t < KEPT && t >= d) v = offp[t - d];
        __syncthreads();
        if (t < KEPT) offp[t] += v;
        __syncthreads();
    }

    {   // scatter u's into per-k sorted list
        int k = dstl[t];
        int pos = offp[k] - cnt[k] + atomicAdd(&fill[k], 1);
        list[pos] = (unsigned short)t;
    }
    __syncthreads();

    float* outb = out + (size_t)b * KEPT * Cn;
    const int qtr = ln >> 4;               // 4 rows per wave, 16 lanes each
    const int cq  = ln & 15;               // c4 = cq, cq+16, cq+32

    for (int pass = 0; pass < 8; ++pass) {
        int k = pass * 32 + wv * 4 + qtr;
        int e = offp[k], c = cnt[k], s0 = e - c;
        const float* xr = xb + (size_t)k * Cn;
        float4 a0 = *reinterpret_cast<const float4*>(xr + cq * 4);
        float4 a1 = *reinterpret_cast<const float4*>(xr + (cq + 16) * 4);
        float4 a2 = *reinterpret_cast<const float4*>(xr + (cq + 32) * 4);
        for (int i = s0; i < e; ++i) {
            const float* xs = xb + (size_t)(KEPT + list[i]) * Cn;
            float4 v0  = *reinterpret_cast<const float4*>(xs + cq * 4);
            float4 v1v = *reinterpret_cast<const float4*>(xs + (cq + 16) * 4);
            float4 v2v = *reinterpret_cast<const float4*>(xs + (cq + 32) * 4);
            a0.x += v0.x;  a0.y += v0.y;  a0.z += v0.z;  a0.w += v0.w;
            a1.x += v1v.x; a1.y += v1v.y; a1.z += v1v.z; a1.w += v1v.w;
            a2.x += v2v.x; a2.y += v2v.y; a2.z += v2v.z; a2.w += v2v.w;
        }
        float rc = 1.0f / ((float)c + 1.0f);
        float* orow = outb + (size_t)k * Cn;
        *reinterpret_cast<float4*>(orow + cq * 4) =
            make_float4(a0.x * rc, a0.y * rc, a0.z * rc, a0.w * rc);
        *reinterpret_cast<float4*>(orow + (cq + 16) * 4) =
            make_float4(a1.x * rc, a1.y * rc, a1.z * rc, a1.w * rc);
        *reinterpret_cast<float4*>(orow + (cq + 32) * 4) =
            make_float4(a2.x * rc, a2.y * rc, a2.z * rc, a2.w * rc);
    }
}

extern "C" void kernel_launch(void* const* d_in, const int* in_sizes, int n_in,
                              void* d_out, int out_size, void* d_ws, size_t ws_size,
                              hipStream_t stream) {
    const float* x = (const float*)d_in[0];
    float* out = (float*)d_out;

    char* ws = (char*)d_ws;
    float* w   = (float*)ws;                               // 512*192 f32
    float* rsw = (float*)(ws + (size_t)512 * Cn * 4);      // 512*192 f32

    norm_kernel<<<dim3(512), dim3(768), 0, stream>>>(x, w, rsw);
    simmerge_kernel<<<dim3(512), dim3(512), 0, stream>>>(x, w, rsw, out);
}

// Round 12
// 379.944 us; speedup vs baseline: 1.1465x; 1.1465x over previous
//
#include <hip/hip_runtime.h>
#include <hip/hip_bf16.h>
#include <math.h>

#define Nn   1024
#define Cn   192
#define KEPT 256
#define COMP 512
#define UT   128
#define KT   64
#define MARGIN 4e-4f
#define WCAP 512

typedef __attribute__((ext_vector_type(8))) _Float16 half8v;
typedef __attribute__((ext_vector_type(4))) float f32x4;

__device__ __forceinline__ unsigned encf(float f) {
    unsigned u = __float_as_uint(f);
    return (u & 0x80000000u) ? ~u : (u | 0x80000000u);
}
// pack 4 floats into one u64 of 4 fp16 (RNE)
__device__ __forceinline__ unsigned long long cvt4(float m0, float m1, float m2, float m3) {
    unsigned short h0 = __builtin_bit_cast(unsigned short, (_Float16)m0);
    unsigned short h1 = __builtin_bit_cast(unsigned short, (_Float16)m1);
    unsigned short h2 = __builtin_bit_cast(unsigned short, (_Float16)m2);
    unsigned short h3 = __builtin_bit_cast(unsigned short, (_Float16)m3);
    return (unsigned long long)h0 | ((unsigned long long)h1 << 16)
         | ((unsigned long long)h2 << 32) | ((unsigned long long)h3 << 48);
}

// ---------------- Kernel A: w = 1/sumsq, rsw = rsqrt(sumsq) ----------------
__global__ __launch_bounds__(768) void norm_kernel(const float* __restrict__ x,
                                                   float* __restrict__ w,
                                                   float* __restrict__ rsw) {
    __shared__ float4 red[16][48];
    int b = blockIdx.x, t = threadIdx.x;
    int c4 = t % 48, ng = t / 48;
    const float* xb = x + (size_t)b * Nn * Cn;
    float4 s = make_float4(0.f, 0.f, 0.f, 0.f);
    for (int i = 0; i < 64; ++i) {
        float4 v = *reinterpret_cast<const float4*>(
            xb + (size_t)(ng * 64 + i) * Cn + c4 * 4);
        s.x += v.x * v.x; s.y += v.y * v.y; s.z += v.z * v.z; s.w += v.w * v.w;
    }
    red[ng][c4] = s;
    __syncthreads();
    if (t < 48) {
        float4 a = make_float4(0.f, 0.f, 0.f, 0.f);
        #pragma unroll
        for (int g = 0; g < 16; ++g) {
            float4 v = red[g][t];
            a.x += v.x; a.y += v.y; a.z += v.z; a.w += v.w;
        }
        float4 wv = make_float4(1.0f / a.x, 1.0f / a.y, 1.0f / a.z, 1.0f / a.w);
        float4 rv = make_float4(rsqrtf(a.x), rsqrtf(a.y), rsqrtf(a.z), rsqrtf(a.w));
        *reinterpret_cast<float4*>(w   + (size_t)b * Cn + t * 4) = wv;
        *reinterpret_cast<float4*>(rsw + (size_t)b * Cn + t * 4) = rv;
    }
}

// ======= Kernel B: one block per b — fp16 MFMA sim (4 u-chunks) + gather merge =======
// LDS ~77.5 KB -> 2 blocks/CU; VGPR left to the allocator (round-11's (512,4) forced
// a 64-VGPR clamp -> 237 MB scratch spill traffic; plain (512) matches round-10 sim).
__global__ __launch_bounds__(512) void simmerge_kernel(const float* __restrict__ x,
                                                       const float* __restrict__ w,
                                                       const float* __restrict__ rsw,
                                                       float* __restrict__ out) {
    __shared__ __align__(16) unsigned short su_h[UT * Cn];    // 49152 B
    __shared__ __align__(16) unsigned short sk_h[KT * Cn];    // 24576 B (merge scratch overlay)
    __shared__ float rl[Cn];                                  //   768 B
    __shared__ float wl[Cn];                                  //   768 B
    __shared__ float rowthr[UT];                              //   512 B
    __shared__ unsigned long long best[UT];                   //  1024 B
    __shared__ unsigned short wlist[WCAP];                    //  1024 B
    __shared__ int nc;                                        //     4 B
    __shared__ unsigned short dstl[COMP];                     //  1024 B  (k < 256 fits u16)

    const int b = blockIdx.x;
    const int t = threadIdx.x;
    const float* xb = x + (size_t)b * Nn * Cn;

    if (t < Cn) { rl[t] = rsw[b * Cn + t]; wl[t] = w[b * Cn + t]; }
    __syncthreads();

    const int wv   = t >> 6;
    const int ln   = t & 63;
    const int l15  = ln & 15;
    const int hi2  = ln >> 4;
    const int akey = (l15 & 7) << 4;
    const int abase = (wv * 16 + l15) * 384;
    int bbase[4];
    #pragma unroll
    for (int j = 0; j < 4; ++j) bbase[j] = (j * 16 + l15) * 384;

    // ---------------- Phase 1: sim + argmax per 128-u chunk ----------------
    for (int uc = 0; uc < 4; ++uc) {
        const int u0 = uc * UT;
        __syncthreads();   // prior-chunk LDS reads done
        if (t < UT) { rowthr[t] = INFINITY; best[t] = 0ull; }
        if (t == 0) nc = 0;
        __syncthreads();

        // stage su (128 unimp rows) as fp16, swizzled
        #pragma unroll
        for (int i = 0; i < 12; ++i) {
            int idx = t + 512 * i;
            int r = idx / 48, c4 = idx % 48;
            float4 v = *reinterpret_cast<const float4*>(
                xb + (size_t)(KEPT + u0 + r) * Cn + c4 * 4);
            unsigned long long h = cvt4(v.x * rl[c4 * 4 + 0], v.y * rl[c4 * 4 + 1],
                                        v.z * rl[c4 * 4 + 2], v.w * rl[c4 * 4 + 3]);
            int byte = r * 384 + ((c4 * 8) ^ ((r & 7) << 4));
            *reinterpret_cast<unsigned long long*>(reinterpret_cast<char*>(su_h) + byte) = h;
        }

        float4 pf[6];
        #pragma unroll
        for (int i = 0; i < 6; ++i) {
            int idx = t + 512 * i;
            int r = idx / 48, c4 = idx % 48;
            pf[i] = *reinterpret_cast<const float4*>(xb + (size_t)r * Cn + c4 * 4);
        }

        f32x4 acc[4][4];
        #pragma unroll
        for (int kt = 0; kt < 4; ++kt)
            #pragma unroll
            for (int j = 0; j < 4; ++j) acc[kt][j] = (f32x4)0.f;

        #pragma unroll
        for (int kt = 0; kt < 4; ++kt) {
            __syncthreads();
            #pragma unroll
            for (int i = 0; i < 6; ++i) {
                int idx = t + 512 * i;
                int r = idx / 48, c4 = idx % 48;
                unsigned long long h = cvt4(pf[i].x * rl[c4 * 4 + 0], pf[i].y * rl[c4 * 4 + 1],
                                            pf[i].z * rl[c4 * 4 + 2], pf[i].w * rl[c4 * 4 + 3]);
                int byte = r * 384 + ((c4 * 8) ^ ((r & 7) << 4));
                *reinterpret_cast<unsigned long long*>(reinterpret_cast<char*>(sk_h) + byte) = h;
            }
            __syncthreads();
            if (kt < 3) {
                #pragma unroll
                for (int i = 0; i < 6; ++i) {
                    int idx = t + 512 * i;
                    int r = idx / 48, c4 = idx % 48;
                    pf[i] = *reinterpret_cast<const float4*>(
                        xb + (size_t)((kt + 1) * KT + r) * Cn + c4 * 4);
                }
            }

            #pragma unroll
            for (int ks = 0; ks < 6; ++ks) {
                int koff = (ks * 64 + hi2 * 16) ^ akey;
                half8v ah = *reinterpret_cast<const half8v*>(
                    reinterpret_cast<const char*>(su_h) + abase + koff);
                #pragma unroll
                for (int j = 0; j < 4; ++j) {
                    half8v bh = *reinterpret_cast<const half8v*>(
                        reinterpret_cast<const char*>(sk_h) + bbase[j] + koff);
                    acc[kt][j] = __builtin_amdgcn_mfma_f32_16x16x32_f16(ah, bh, acc[kt][j], 0, 0, 0);
                }
            }
        }

        // ---- top-2 (value, argmax-with-lowest-k, 2nd value) per row ----
        float v1[4], v2[4];
        int   i1[4];
        #pragma unroll
        for (int r = 0; r < 4; ++r) { v1[r] = -INFINITY; v2[r] = -INFINITY; i1[r] = 1; }

        #pragma unroll
        for (int kt = 0; kt < 4; ++kt)
            #pragma unroll
            for (int j = 0; j < 4; ++j) {
                int k = kt * KT + j * 16 + l15;
                #pragma unroll
                for (int r = 0; r < 4; ++r) {
                    float v = acc[kt][j][r];
                    if (k != 0) {
                        if (v > v1[r]) { v2[r] = v1[r]; v1[r] = v; i1[r] = k; }
                        else if (v > v2[r]) v2[r] = v;
                    }
                }
            }

        #pragma unroll
        for (int r = 0; r < 4; ++r) {
            #pragma unroll
            for (int off = 1; off < 16; off <<= 1) {
                float ov1 = __shfl_xor(v1[r], off);
                int   oi1 = __shfl_xor(i1[r], off);
                float ov2 = __shfl_xor(v2[r], off);
                if (ov1 > v1[r] || (ov1 == v1[r] && oi1 < i1[r])) {
                    v2[r] = fmaxf(v1[r], ov2);
                    v1[r] = ov1; i1[r] = oi1;
                } else {
                    v2[r] = fmaxf(v2[r], ov1);
                }
            }
        }

        if (l15 == 0) {
            #pragma unroll
            for (int r = 0; r < 4; ++r) {
                int ur = wv * 16 + hi2 * 4 + r;
                if (v1[r] - v2[r] > MARGIN) dstl[u0 + ur] = (unsigned short)i1[r];
                else rowthr[ur] = v1[r] - MARGIN;
            }
        }
        __syncthreads();

        // ---- candidate push for flagged rows ----
        #pragma unroll
        for (int kt = 0; kt < 4; ++kt)
            #pragma unroll
            for (int j = 0; j < 4; ++j) {
                int k = kt * KT + j * 16 + l15;
                if (k == 0) continue;
                #pragma unroll
                for (int r = 0; r < 4; ++r) {
                    int ur = wv * 16 + hi2 * 4 + r;
                    if (acc[kt][j][r] >= rowthr[ur]) {
                        int pos = atomicAdd(&nc, 1);
                        if (pos < WCAP)
                            wlist[pos] = (unsigned short)((ur << 8) | k);
                    }
                }
            }
        __syncthreads();

        // ---- wave-parallel exact fp32 rescue ----
        int n = nc < WCAP ? nc : WCAP;
        for (int ci = wv; ci < n; ci += 8) {
            unsigned item = wlist[ci];
            int ur = item >> 8, k = item & 255;
            const float* xu = xb + (size_t)(KEPT + u0 + ur) * Cn;
            const float* xk = xb + (size_t)k * Cn;
            float p = 0.f;
            if (ln < 48) {
                float4 a  = *reinterpret_cast<const float4*>(xu + ln * 4);
                float4 b4 = *reinterpret_cast<const float4*>(xk + ln * 4);
                p = a.x * b4.x * wl[ln * 4 + 0] + a.y * b4.y * wl[ln * 4 + 1]
                  + a.z * b4.z * wl[ln * 4 + 2] + a.w * b4.w * wl[ln * 4 + 3];
            }
            #pragma unroll
            for (int off = 32; off >= 1; off >>= 1) p += __shfl_xor(p, off);
            if (ln == 0) {
                unsigned long long e = ((unsigned long long)encf(p) << 32)
                                     | (unsigned long long)(0xFFFFFFFFu - (unsigned)k);
                atomicMax(&best[ur], e);
            }
        }
        __syncthreads();

        if (t < UT && rowthr[t] < 3.0e38f) {
            unsigned k = 0xFFFFFFFFu - (unsigned)(best[t] & 0xFFFFFFFFull);
            dstl[u0 + t] = (unsigned short)k;
        }
    }
    __syncthreads();

    // ---------------- Phase 2: counting-sort gather merge (scratch overlays sk_h) ----------------
    int* cnt  = reinterpret_cast<int*>(sk_h);          // 1024 B
    int* offp = cnt + KEPT;                            // 1024 B
    int* fill = offp + KEPT;                           // 1024 B
    unsigned short* list = reinterpret_cast<unsigned short*>(fill + KEPT);  // 1024 B

    if (t < KEPT) { cnt[t] = 0; fill[t] = 0; }
    __syncthreads();
    atomicAdd(&cnt[dstl[t]], 1);
    __syncthreads();

    if (t < KEPT) offp[t] = cnt[t];
    __syncthreads();
    #pragma unroll
    for (int d = 1; d < KEPT; d <<= 1) {     // Hillis-Steele inclusive scan
        int v = 0;
        if (t < KEPT && t >= d) v = offp[t - d];
        __syncthreads();
        if (t < KEPT) offp[t] += v;
        __syncthreads();
    }

    {   // scatter u's into per-k sorted list
        int k = dstl[t];
        int pos = offp[k] - cnt[k] + atomicAdd(&fill[k], 1);
        list[pos] = (unsigned short)t;
    }
    __syncthreads();

    float* outb = out + (size_t)b * KEPT * Cn;
    const int qtr = ln >> 4;               // 4 rows per wave, 16 lanes each
    const int cq  = ln & 15;               // c4 = cq, cq+16, cq+32

    for (int pass = 0; pass < 8; ++pass) {
        int k = pass * 32 + wv * 4 + qtr;
        int e = offp[k], c = cnt[k], s0 = e - c;
        const float* xr = xb + (size_t)k * Cn;
        float4 a0 = *reinterpret_cast<const float4*>(xr + cq * 4);
        float4 a1 = *reinterpret_cast<const float4*>(xr + (cq + 16) * 4);
        float4 a2 = *reinterpret_cast<const float4*>(xr + (cq + 32) * 4);
        for (int i = s0; i < e; ++i) {
            const float* xs = xb + (size_t)(KEPT + list[i]) * Cn;
            float4 v0  = *reinterpret_cast<const float4*>(xs + cq * 4);
            float4 v1v = *reinterpret_cast<const float4*>(xs + (cq + 16) * 4);
            float4 v2v = *reinterpret_cast<const float4*>(xs + (cq + 32) * 4);
            a0.x += v0.x;  a0.y += v0.y;  a0.z += v0.z;  a0.w += v0.w;
            a1.x += v1v.x; a1.y += v1v.y; a1.z += v1v.z; a1.w += v1v.w;
            a2.x += v2v.x; a2.y += v2v.y; a2.z += v2v.z; a2.w += v2v.w;
        }
        float rc = 1.0f / ((float)c + 1.0f);
        float* orow = outb + (size_t)k * Cn;
        *reinterpret_cast<float4*>(orow + cq * 4) =
            make_float4(a0.x * rc, a0.y * rc, a0.z * rc, a0.w * rc);
        *reinterpret_cast<float4*>(orow + (cq + 16) * 4) =
            make_float4(a1.x * rc, a1.y * rc, a1.z * rc, a1.w * rc);
        *reinterpret_cast<float4*>(orow + (cq + 32) * 4) =
            make_float4(a2.x * rc, a2.y * rc, a2.z * rc, a2.w * rc);
    }
}

extern "C" void kernel_launch(void* const* d_in, const int* in_sizes, int n_in,
                              void* d_out, int out_size, void* d_ws, size_t ws_size,
                              hipStream_t stream) {
    const float* x = (const float*)d_in[0];
    float* out = (float*)d_out;

    char* ws = (char*)d_ws;
    float* w   = (float*)ws;                               // 512*192 f32
    float* rsw = (float*)(ws + (size_t)512 * Cn * 4);      // 512*192 f32

    norm_kernel<<<dim3(512), dim3(768), 0, stream>>>(x, w, rsw);
    simmerge_kernel<<<dim3(512), dim3(512), 0, stream>>>(x, w, rsw, out);
}

// Round 13
// 329.035 us; speedup vs baseline: 1.3238x; 1.1547x over previous
//
#include <hip/hip_runtime.h>
#include <hip/hip_bf16.h>
#include <math.h>

#define Nn   1024
#define Cn   192
#define KEPT 256
#define COMP 512
#define UCH  64          // u-rows per sim block
#define KT   32          // k-rows per LDS tile
#define MARGIN 4e-4f
#define WCAP 256

typedef __attribute__((ext_vector_type(8))) _Float16 half8v;
typedef __attribute__((ext_vector_type(4))) float f32x4;

__device__ __forceinline__ unsigned encf(float f) {
    unsigned u = __float_as_uint(f);
    return (u & 0x80000000u) ? ~u : (u | 0x80000000u);
}
// pack 4 floats into one u64 of 4 fp16 (RNE)
__device__ __forceinline__ unsigned long long cvt4(float m0, float m1, float m2, float m3) {
    unsigned short h0 = __builtin_bit_cast(unsigned short, (_Float16)m0);
    unsigned short h1 = __builtin_bit_cast(unsigned short, (_Float16)m1);
    unsigned short h2 = __builtin_bit_cast(unsigned short, (_Float16)m2);
    unsigned short h3 = __builtin_bit_cast(unsigned short, (_Float16)m3);
    return (unsigned long long)h0 | ((unsigned long long)h1 << 16)
         | ((unsigned long long)h2 << 32) | ((unsigned long long)h3 << 48);
}

// ---------------- Kernel A: w = 1/sumsq, rsw = rsqrt(sumsq) ----------------
__global__ __launch_bounds__(768) void norm_kernel(const float* __restrict__ x,
                                                   float* __restrict__ w,
                                                   float* __restrict__ rsw) {
    __shared__ float4 red[16][48];
    int b = blockIdx.x, t = threadIdx.x;
    int c4 = t % 48, ng = t / 48;
    const float* xb = x + (size_t)b * Nn * Cn;
    float4 s = make_float4(0.f, 0.f, 0.f, 0.f);
    for (int i = 0; i < 64; ++i) {
        float4 v = *reinterpret_cast<const float4*>(
            xb + (size_t)(ng * 64 + i) * Cn + c4 * 4);
        s.x += v.x * v.x; s.y += v.y * v.y; s.z += v.z * v.z; s.w += v.w * v.w;
    }
    red[ng][c4] = s;
    __syncthreads();
    if (t < 48) {
        float4 a = make_float4(0.f, 0.f, 0.f, 0.f);
        #pragma unroll
        for (int g = 0; g < 16; ++g) {
            float4 v = red[g][t];
            a.x += v.x; a.y += v.y; a.z += v.z; a.w += v.w;
        }
        float4 wv = make_float4(1.0f / a.x, 1.0f / a.y, 1.0f / a.z, 1.0f / a.w);
        float4 rv = make_float4(rsqrtf(a.x), rsqrtf(a.y), rsqrtf(a.z), rsqrtf(a.w));
        *reinterpret_cast<float4*>(w   + (size_t)b * Cn + t * 4) = wv;
        *reinterpret_cast<float4*>(rsw + (size_t)b * Cn + t * 4) = rv;
    }
}

// ------- Kernel B: fp16 MFMA sim, A-frags in registers, 256 thr / 64-u chunk -------
// grid 4096: bi -> xcd=bi&7, slot=bi>>3, b=xcd*64+(slot>>3), u0=(slot&7)*64.
// LDS ~15.5 KB; __launch_bounds__(256,3) -> 170 regs/wave (106 arch + 64 AGPR) -> 12 waves/CU.
__global__ __launch_bounds__(256, 3) void sim_kernel(const float* __restrict__ x,
                                                     const float* __restrict__ w,
                                                     const float* __restrict__ rsw,
                                                     int* __restrict__ dst_idx) {
    __shared__ __align__(16) unsigned short sk_h[KT * Cn];    // 12288 B
    __shared__ float rl[Cn];
    __shared__ float wl[Cn];
    __shared__ float rowthr[UCH];
    __shared__ unsigned long long best[UCH];
    __shared__ unsigned short wlist[WCAP];
    __shared__ int nc;

    const int bi   = blockIdx.x;
    const int xcd  = bi & 7;
    const int slot = bi >> 3;
    const int b    = xcd * 64 + (slot >> 3);
    const int u0   = (slot & 7) * UCH;
    const int t    = threadIdx.x;
    const float* xb = x + (size_t)b * Nn * Cn;

    if (t < Cn) { rl[t] = rsw[b * Cn + t]; wl[t] = w[b * Cn + t]; }
    if (t < UCH) { rowthr[t] = INFINITY; best[t] = 0ull; }
    if (t == 0) nc = 0;
    __syncthreads();

    const int wv   = t >> 6;        // 0..3
    const int ln   = t & 63;
    const int l15  = ln & 15;
    const int hi2  = ln >> 4;
    const int akey = (l15 & 7) << 4;
    int bbase[2];
    #pragma unroll
    for (int j = 0; j < 2; ++j) bbase[j] = (j * 16 + l15) * 384;

    // ---- A-fragments in registers: this lane's u-row, all 6 k-slices ----
    half8v af[6];
    {
        const float* arow = xb + (size_t)(KEPT + u0 + wv * 16 + l15) * Cn;
        #pragma unroll
        for (int ks = 0; ks < 6; ++ks) {
            int c0 = ks * 32 + hi2 * 8;
            float4 v0 = *reinterpret_cast<const float4*>(arow + c0);
            float4 v1 = *reinterpret_cast<const float4*>(arow + c0 + 4);
            half8v a;
            a[0] = (_Float16)(v0.x * rl[c0 + 0]);
            a[1] = (_Float16)(v0.y * rl[c0 + 1]);
            a[2] = (_Float16)(v0.z * rl[c0 + 2]);
            a[3] = (_Float16)(v0.w * rl[c0 + 3]);
            a[4] = (_Float16)(v1.x * rl[c0 + 4]);
            a[5] = (_Float16)(v1.y * rl[c0 + 5]);
            a[6] = (_Float16)(v1.z * rl[c0 + 6]);
            a[7] = (_Float16)(v1.w * rl[c0 + 7]);
            af[ks] = a;
        }
    }

    f32x4 acc[8][2];
    #pragma unroll
    for (int kt = 0; kt < 8; ++kt)
        #pragma unroll
        for (int j = 0; j < 2; ++j) acc[kt][j] = (f32x4)0.f;

    #pragma unroll
    for (int kt = 0; kt < 8; ++kt) {
        __syncthreads();   // prior tile's reads done
        #pragma unroll
        for (int i = 0; i < 6; ++i) {      // stage sk tile (32 k-rows), swizzled
            int idx = t + 256 * i;         // 0..1535
            int r = idx / 48, c4 = idx % 48;
            float4 v = *reinterpret_cast<const float4*>(
                xb + (size_t)(kt * KT + r) * Cn + c4 * 4);
            unsigned long long h = cvt4(v.x * rl[c4 * 4 + 0], v.y * rl[c4 * 4 + 1],
                                        v.z * rl[c4 * 4 + 2], v.w * rl[c4 * 4 + 3]);
            int byte = r * 384 + ((c4 * 8) ^ ((r & 7) << 4));
            *reinterpret_cast<unsigned long long*>(reinterpret_cast<char*>(sk_h) + byte) = h;
        }
        __syncthreads();

        #pragma unroll
        for (int ks = 0; ks < 6; ++ks) {
            int koff = (ks * 64 + hi2 * 16) ^ akey;
            #pragma unroll
            for (int j = 0; j < 2; ++j) {
                half8v bh = *reinterpret_cast<const half8v*>(
                    reinterpret_cast<const char*>(sk_h) + bbase[j] + koff);
                acc[kt][j] = __builtin_amdgcn_mfma_f32_16x16x32_f16(af[ks], bh, acc[kt][j], 0, 0, 0);
            }
        }
    }

    // ---- top-2 (value, argmax-with-lowest-k, 2nd value) per row ----
    float v1[4], v2[4];
    int   i1[4];
    #pragma unroll
    for (int r = 0; r < 4; ++r) { v1[r] = -INFINITY; v2[r] = -INFINITY; i1[r] = 1; }

    #pragma unroll
    for (int kt = 0; kt < 8; ++kt)
        #pragma unroll
        for (int j = 0; j < 2; ++j) {
            int k = kt * KT + j * 16 + l15;
            #pragma unroll
            for (int r = 0; r < 4; ++r) {
                float v = acc[kt][j][r];
                if (k != 0) {
                    if (v > v1[r]) { v2[r] = v1[r]; v1[r] = v; i1[r] = k; }
                    else if (v > v2[r]) v2[r] = v;
                }
            }
        }

    #pragma unroll
    for (int r = 0; r < 4; ++r) {
        #pragma unroll
        for (int off = 1; off < 16; off <<= 1) {
            float ov1 = __shfl_xor(v1[r], off);
            int   oi1 = __shfl_xor(i1[r], off);
            float ov2 = __shfl_xor(v2[r], off);
            if (ov1 > v1[r] || (ov1 == v1[r] && oi1 < i1[r])) {
                v2[r] = fmaxf(v1[r], ov2);
                v1[r] = ov1; i1[r] = oi1;
            } else {
                v2[r] = fmaxf(v2[r], ov1);
            }
        }
    }

    if (l15 == 0) {
        #pragma unroll
        for (int r = 0; r < 4; ++r) {
            int ur = wv * 16 + hi2 * 4 + r;
            if (v1[r] - v2[r] > MARGIN) dst_idx[b * COMP + u0 + ur] = i1[r];
            else rowthr[ur] = v1[r] - MARGIN;
        }
    }
    __syncthreads();

    // ---- candidate push for flagged rows ----
    #pragma unroll
    for (int kt = 0; kt < 8; ++kt)
        #pragma unroll
        for (int j = 0; j < 2; ++j) {
            int k = kt * KT + j * 16 + l15;
            if (k == 0) continue;
            #pragma unroll
            for (int r = 0; r < 4; ++r) {
                int ur = wv * 16 + hi2 * 4 + r;
                if (acc[kt][j][r] >= rowthr[ur]) {
                    int pos = atomicAdd(&nc, 1);
                    if (pos < WCAP)
                        wlist[pos] = (unsigned short)((ur << 8) | k);
                }
            }
        }
    __syncthreads();

    // ---- wave-parallel exact fp32 rescue ----
    int n = nc < WCAP ? nc : WCAP;
    for (int ci = wv; ci < n; ci += 4) {
        unsigned item = wlist[ci];
        int ur = item >> 8, k = item & 255;
        const float* xu = xb + (size_t)(KEPT + u0 + ur) * Cn;
        const float* xk = xb + (size_t)k * Cn;
        float p = 0.f;
        if (ln < 48) {
            float4 a  = *reinterpret_cast<const float4*>(xu + ln * 4);
            float4 b4 = *reinterpret_cast<const float4*>(xk + ln * 4);
            p = a.x * b4.x * wl[ln * 4 + 0] + a.y * b4.y * wl[ln * 4 + 1]
              + a.z * b4.z * wl[ln * 4 + 2] + a.w * b4.w * wl[ln * 4 + 3];
        }
        #pragma unroll
        for (int off = 32; off >= 1; off >>= 1) p += __shfl_xor(p, off);
        if (ln == 0) {
            unsigned long long e = ((unsigned long long)encf(p) << 32)
                                 | (unsigned long long)(0xFFFFFFFFu - (unsigned)k);
            atomicMax(&best[ur], e);
        }
    }
    __syncthreads();

    if (t < UCH && rowthr[t] < 3.0e38f) {
        unsigned k = 0xFFFFFFFFu - (unsigned)(best[t] & 0xFFFFFFFFull);
        dst_idx[b * COMP + u0 + t] = (int)k;
    }
}

// ------- Kernel C: counting-sort gather merge, 4 rows/wave geometry -------
__global__ __launch_bounds__(512) void merge_kernel(const float* __restrict__ x,
                                                    const int* __restrict__ dst_idx,
                                                    float* __restrict__ out) {
    __shared__ int sidx[COMP];
    __shared__ int cnt[KEPT];
    __shared__ int off[KEPT];     // inclusive prefix sum
    __shared__ int fill[KEPT];
    __shared__ unsigned short list[COMP];

    int b = blockIdx.x, t = threadIdx.x;

    if (t < KEPT) { cnt[t] = 0; fill[t] = 0; }
    sidx[t] = dst_idx[b * COMP + t];
    __syncthreads();
    atomicAdd(&cnt[sidx[t]], 1);
    __syncthreads();

    if (t < KEPT) off[t] = cnt[t];
    __syncthreads();
    #pragma unroll
    for (int d = 1; d < KEPT; d <<= 1) {     // Hillis-Steele inclusive scan
        int v = 0;
        if (t < KEPT && t >= d) v = off[t - d];
        __syncthreads();
        if (t < KEPT) off[t] += v;
        __syncthreads();
    }

    {   // scatter u's into per-k sorted list
        int k = sidx[t];
        int pos = off[k] - cnt[k] + atomicAdd(&fill[k], 1);
        list[pos] = (unsigned short)t;
    }
    __syncthreads();

    const float* xb   = x   + (size_t)b * Nn * Cn;
    float*       outb = out + (size_t)b * KEPT * Cn;
    const int wv  = t >> 6, ln = t & 63;
    const int qtr = ln >> 4;               // 4 rows per wave, 16 lanes each
    const int cq  = ln & 15;               // c4 = cq, cq+16, cq+32

    for (int pass = 0; pass < 8; ++pass) {
        int k = pass * 32 + wv * 4 + qtr;
        int e = off[k], c = cnt[k], s0 = e - c;
        const float* xr = xb + (size_t)k * Cn;
        float4 a0 = *reinterpret_cast<const float4*>(xr + cq * 4);
        float4 a1 = *reinterpret_cast<const float4*>(xr + (cq + 16) * 4);
        float4 a2 = *reinterpret_cast<const float4*>(xr + (cq + 32) * 4);
        for (int i = s0; i < e; ++i) {
            const float* xs = xb + (size_t)(KEPT + list[i]) * Cn;
            float4 v0  = *reinterpret_cast<const float4*>(xs + cq * 4);
            float4 v1v = *reinterpret_cast<const float4*>(xs + (cq + 16) * 4);
            float4 v2v = *reinterpret_cast<const float4*>(xs + (cq + 32) * 4);
            a0.x += v0.x;  a0.y += v0.y;  a0.z += v0.z;  a0.w += v0.w;
            a1.x += v1v.x; a1.y += v1v.y; a1.z += v1v.z; a1.w += v1v.w;
            a2.x += v2v.x; a2.y += v2v.y; a2.z += v2v.z; a2.w += v2v.w;
        }
        float rc = 1.0f / ((float)c + 1.0f);
        float* orow = outb + (size_t)k * Cn;
        *reinterpret_cast<float4*>(orow + cq * 4) =
            make_float4(a0.x * rc, a0.y * rc, a0.z * rc, a0.w * rc);
        *reinterpret_cast<float4*>(orow + (cq + 16) * 4) =
            make_float4(a1.x * rc, a1.y * rc, a1.z * rc, a1.w * rc);
        *reinterpret_cast<float4*>(orow + (cq + 32) * 4) =
            make_float4(a2.x * rc, a2.y * rc, a2.z * rc, a2.w * rc);
    }
}

extern "C" void kernel_launch(void* const* d_in, const int* in_sizes, int n_in,
                              void* d_out, int out_size, void* d_ws, size_t ws_size,
                              hipStream_t stream) {
    const float* x = (const float*)d_in[0];
    float* out = (float*)d_out;

    char* ws = (char*)d_ws;
    float* w       = (float*)ws;                               // 512*192 f32
    float* rsw     = (float*)(ws + (size_t)512 * Cn * 4);      // 512*192 f32
    int*   dst_idx = (int*)  (ws + (size_t)2 * 512 * Cn * 4);  // 512*512 i32

    norm_kernel<<<dim3(512), dim3(768), 0, stream>>>(x, w, rsw);
    sim_kernel<<<dim3(4096), dim3(256), 0, stream>>>(x, w, rsw, dst_idx);
    merge_kernel<<<dim3(512), dim3(512), 0, stream>>>(x, dst_idx, out);
}

// Round 14
// 304.340 us; speedup vs baseline: 1.4313x; 1.0811x over previous
//
#include <hip/hip_runtime.h>
#include <hip/hip_bf16.h>
#include <math.h>

#define Nn   1024
#define Cn   192
#define KEPT 256
#define COMP 512
#define UT   128
#define KT   64
#define MARGIN 4e-4f
#define WCAP 512

typedef __attribute__((ext_vector_type(8))) _Float16 half8v;
typedef __attribute__((ext_vector_type(4))) float f32x4;

__device__ __forceinline__ unsigned encf(float f) {
    unsigned u = __float_as_uint(f);
    return (u & 0x80000000u) ? ~u : (u | 0x80000000u);
}
// pack 4 floats into one u64 of 4 fp16 (RNE)
__device__ __forceinline__ unsigned long long cvt4(float m0, float m1, float m2, float m3) {
    unsigned short h0 = __builtin_bit_cast(unsigned short, (_Float16)m0);
    unsigned short h1 = __builtin_bit_cast(unsigned short, (_Float16)m1);
    unsigned short h2 = __builtin_bit_cast(unsigned short, (_Float16)m2);
    unsigned short h3 = __builtin_bit_cast(unsigned short, (_Float16)m3);
    return (unsigned long long)h0 | ((unsigned long long)h1 << 16)
         | ((unsigned long long)h2 << 32) | ((unsigned long long)h3 << 48);
}

// ---------------- Kernel A: w = 1/sumsq, rsw = rsqrt(sumsq) ----------------
__global__ __launch_bounds__(768) void norm_kernel(const float* __restrict__ x,
                                                   float* __restrict__ w,
                                                   float* __restrict__ rsw) {
    __shared__ float4 red[16][48];
    int b = blockIdx.x, t = threadIdx.x;
    int c4 = t % 48, ng = t / 48;
    const float* xb = x + (size_t)b * Nn * Cn;
    float4 s = make_float4(0.f, 0.f, 0.f, 0.f);
    for (int i = 0; i < 64; ++i) {
        float4 v = *reinterpret_cast<const float4*>(
            xb + (size_t)(ng * 64 + i) * Cn + c4 * 4);
        s.x += v.x * v.x; s.y += v.y * v.y; s.z += v.z * v.z; s.w += v.w * v.w;
    }
    red[ng][c4] = s;
    __syncthreads();
    if (t < 48) {
        float4 a = make_float4(0.f, 0.f, 0.f, 0.f);
        #pragma unroll
        for (int g = 0; g < 16; ++g) {
            float4 v = red[g][t];
            a.x += v.x; a.y += v.y; a.z += v.z; a.w += v.w;
        }
        float4 wv = make_float4(1.0f / a.x, 1.0f / a.y, 1.0f / a.z, 1.0f / a.w);
        float4 rv = make_float4(rsqrtf(a.x), rsqrtf(a.y), rsqrtf(a.z), rsqrtf(a.w));
        *reinterpret_cast<float4*>(w   + (size_t)b * Cn + t * 4) = wv;
        *reinterpret_cast<float4*>(rsw + (size_t)b * Cn + t * 4) = rv;
    }
}

// ------- Kernel B: fp16 MFMA sim + top-2 gap test + wave-parallel exact rescue -------
// 1-D grid 2048, decoded so the 4 u-blocks of each b share an XCD (i%8 round-robin).
// A-fragments hoisted to registers (kt-invariant LDS reads done once).
__global__ __launch_bounds__(512) void sim_kernel(const float* __restrict__ x,
                                                  const float* __restrict__ w,
                                                  const float* __restrict__ rsw,
                                                  int* __restrict__ dst_idx) {
    __shared__ __align__(16) unsigned short su_h[UT * Cn];    // 49152 B
    __shared__ __align__(16) unsigned short sk_h[KT * Cn];    // 24576 B
    __shared__ float rl[Cn];
    __shared__ float wl[Cn];
    __shared__ float rowthr[UT];
    __shared__ unsigned long long best[UT];
    __shared__ unsigned short wlist[WCAP];
    __shared__ int nc;

    const int bi   = blockIdx.x;
    const int xcd  = bi & 7;
    const int slot = bi >> 3;
    const int b    = xcd * 64 + (slot >> 2);
    const int u0   = (slot & 3) * UT;
    const int t    = threadIdx.x;
    const float* xb = x + (size_t)b * Nn * Cn;

    if (t < Cn) { rl[t] = rsw[b * Cn + t]; wl[t] = w[b * Cn + t]; }
    if (t < UT) { rowthr[t] = INFINITY; best[t] = 0ull; }
    if (t == 0) nc = 0;
    __syncthreads();

    // ---- stage su (128 unimp rows) as fp16, swizzled ----
    #pragma unroll
    for (int i = 0; i < 12; ++i) {
        int idx = t + 512 * i;
        int r = idx / 48, c4 = idx % 48;
        float4 v = *reinterpret_cast<const float4*>(
            xb + (size_t)(KEPT + u0 + r) * Cn + c4 * 4);
        unsigned long long h = cvt4(v.x * rl[c4 * 4 + 0], v.y * rl[c4 * 4 + 1],
                                    v.z * rl[c4 * 4 + 2], v.w * rl[c4 * 4 + 3]);
        int byte = r * 384 + ((c4 * 8) ^ ((r & 7) << 4));
        *reinterpret_cast<unsigned long long*>(reinterpret_cast<char*>(su_h) + byte) = h;
    }

    float4 pf[6];
    #pragma unroll
    for (int i = 0; i < 6; ++i) {
        int idx = t + 512 * i;
        int r = idx / 48, c4 = idx % 48;
        pf[i] = *reinterpret_cast<const float4*>(xb + (size_t)r * Cn + c4 * 4);
    }

    const int wv   = t >> 6;
    const int ln   = t & 63;
    const int l15  = ln & 15;
    const int hi2  = ln >> 4;
    const int akey = (l15 & 7) << 4;
    const int abase = (wv * 16 + l15) * 384;
    int bbase[4];
    #pragma unroll
    for (int j = 0; j < 4; ++j) bbase[j] = (j * 16 + l15) * 384;

    __syncthreads();   // su visible to all waves

    // ---- hoist A-fragments (kt-invariant) into registers ----
    half8v ahr[6];
    #pragma unroll
    for (int ks = 0; ks < 6; ++ks) {
        int koff = (ks * 64 + hi2 * 16) ^ akey;
        ahr[ks] = *reinterpret_cast<const half8v*>(
            reinterpret_cast<const char*>(su_h) + abase + koff);
    }

    f32x4 acc[4][4];
    #pragma unroll
    for (int kt = 0; kt < 4; ++kt)
        #pragma unroll
        for (int j = 0; j < 4; ++j) acc[kt][j] = (f32x4)0.f;

    #pragma unroll
    for (int kt = 0; kt < 4; ++kt) {
        #pragma unroll
        for (int i = 0; i < 6; ++i) {      // write sk tile from prefetched regs
            int idx = t + 512 * i;
            int r = idx / 48, c4 = idx % 48;
            unsigned long long h = cvt4(pf[i].x * rl[c4 * 4 + 0], pf[i].y * rl[c4 * 4 + 1],
                                        pf[i].z * rl[c4 * 4 + 2], pf[i].w * rl[c4 * 4 + 3]);
            int byte = r * 384 + ((c4 * 8) ^ ((r & 7) << 4));
            *reinterpret_cast<unsigned long long*>(reinterpret_cast<char*>(sk_h) + byte) = h;
        }
        __syncthreads();                   // sk visible
        if (kt < 3) {                      // T14: issue next tile's loads now
            #pragma unroll
            for (int i = 0; i < 6; ++i) {
                int idx = t + 512 * i;
                int r = idx / 48, c4 = idx % 48;
                pf[i] = *reinterpret_cast<const float4*>(
                    xb + (size_t)((kt + 1) * KT + r) * Cn + c4 * 4);
            }
        }

        #pragma unroll
        for (int ks = 0; ks < 6; ++ks) {
            int koff = (ks * 64 + hi2 * 16) ^ akey;
            #pragma unroll
            for (int j = 0; j < 4; ++j) {
                half8v bh = *reinterpret_cast<const half8v*>(
                    reinterpret_cast<const char*>(sk_h) + bbase[j] + koff);
                acc[kt][j] = __builtin_amdgcn_mfma_f32_16x16x32_f16(ahr[ks], bh, acc[kt][j], 0, 0, 0);
            }
        }
        __syncthreads();                   // all reads done before next kt's write
    }

    // ---- top-2 (value, argmax-with-lowest-k, 2nd value) per row ----
    float v1[4], v2[4];
    int   i1[4];
    #pragma unroll
    for (int r = 0; r < 4; ++r) { v1[r] = -INFINITY; v2[r] = -INFINITY; i1[r] = 1; }

    #pragma unroll
    for (int kt = 0; kt < 4; ++kt)
        #pragma unroll
        for (int j = 0; j < 4; ++j) {
            int k = kt * KT + j * 16 + l15;
            #pragma unroll
            for (int r = 0; r < 4; ++r) {
                float v = acc[kt][j][r];
                if (k != 0) {
                    if (v > v1[r]) { v2[r] = v1[r]; v1[r] = v; i1[r] = k; }
                    else if (v > v2[r]) v2[r] = v;
                }
            }
        }

    #pragma unroll
    for (int r = 0; r < 4; ++r) {
        #pragma unroll
        for (int off = 1; off < 16; off <<= 1) {
            float ov1 = __shfl_xor(v1[r], off);
            int   oi1 = __shfl_xor(i1[r], off);
            float ov2 = __shfl_xor(v2[r], off);
            if (ov1 > v1[r] || (ov1 == v1[r] && oi1 < i1[r])) {
                v2[r] = fmaxf(v1[r], ov2);
                v1[r] = ov1; i1[r] = oi1;
            } else {
                v2[r] = fmaxf(v2[r], ov1);
            }
        }
    }

    if (l15 == 0) {
        #pragma unroll
        for (int r = 0; r < 4; ++r) {
            int ur = wv * 16 + hi2 * 4 + r;
            if (v1[r] - v2[r] > MARGIN) dst_idx[b * COMP + u0 + ur] = i1[r];
            else rowthr[ur] = v1[r] - MARGIN;
        }
    }
    __syncthreads();

    // ---- candidate push for flagged rows ----
    #pragma unroll
    for (int kt = 0; kt < 4; ++kt)
        #pragma unroll
        for (int j = 0; j < 4; ++j) {
            int k = kt * KT + j * 16 + l15;
            if (k == 0) continue;
            #pragma unroll
            for (int r = 0; r < 4; ++r) {
                int ur = wv * 16 + hi2 * 4 + r;
                if (acc[kt][j][r] >= rowthr[ur]) {
                    int pos = atomicAdd(&nc, 1);
                    if (pos < WCAP)
                        wlist[pos] = (unsigned short)((ur << 8) | k);
                }
            }
        }
    __syncthreads();

    // ---- wave-parallel exact fp32 rescue ----
    int n = nc < WCAP ? nc : WCAP;
    for (int ci = wv; ci < n; ci += 8) {
        unsigned item = wlist[ci];
        int ur = item >> 8, k = item & 255;
        const float* xu = xb + (size_t)(KEPT + u0 + ur) * Cn;
        const float* xk = xb + (size_t)k * Cn;
        float p = 0.f;
        if (ln < 48) {
            float4 a  = *reinterpret_cast<const float4*>(xu + ln * 4);
            float4 b4 = *reinterpret_cast<const float4*>(xk + ln * 4);
            p = a.x * b4.x * wl[ln * 4 + 0] + a.y * b4.y * wl[ln * 4 + 1]
              + a.z * b4.z * wl[ln * 4 + 2] + a.w * b4.w * wl[ln * 4 + 3];
        }
        #pragma unroll
        for (int off = 32; off >= 1; off >>= 1) p += __shfl_xor(p, off);
        if (ln == 0) {
            unsigned long long e = ((unsigned long long)encf(p) << 32)
                                 | (unsigned long long)(0xFFFFFFFFu - (unsigned)k);
            atomicMax(&best[ur], e);
        }
    }
    __syncthreads();

    if (t < UT && rowthr[t] < 3.0e38f) {
        unsigned k = 0xFFFFFFFFu - (unsigned)(best[t] & 0xFFFFFFFFull);
        dst_idx[b * COMP + u0 + t] = (int)k;
    }
}

// ------- Kernel C: counting-sort gather merge, k-split 2-way, wave-shuffle scan -------
// grid (512, 2): block (b, half) gathers k in [half*128, half*128+128).
__global__ __launch_bounds__(512) void merge_kernel(const float* __restrict__ x,
                                                    const int* __restrict__ dst_idx,
                                                    float* __restrict__ out) {
    __shared__ int sidx[COMP];
    __shared__ int cnt[KEPT];
    __shared__ int offp[KEPT];    // inclusive prefix sum
    __shared__ int fill[KEPT];
    __shared__ unsigned short list[COMP];
    __shared__ int wsum[4];

    int b = blockIdx.x, half = blockIdx.y, t = threadIdx.x;

    if (t < KEPT) { cnt[t] = 0; fill[t] = 0; }
    sidx[t] = dst_idx[b * COMP + t];
    __syncthreads();
    atomicAdd(&cnt[sidx[t]], 1);
    __syncthreads();

    // wave-shuffle inclusive scan over 256 bins (waves 0..3)
    int v = 0;
    if (t < KEPT) {
        v = cnt[t];
        int lane = t & 63;
        #pragma unroll
        for (int off = 1; off < 64; off <<= 1) {
            int u = __shfl_up(v, off);
            if (lane >= off) v += u;
        }
        if (lane == 63) wsum[t >> 6] = v;
    }
    __syncthreads();
    if (t < KEPT) {
        int wid = t >> 6;
        if (wid > 0) v += wsum[0];
        if (wid > 1) v += wsum[1];
        if (wid > 2) v += wsum[2];
        offp[t] = v;
    }
    __syncthreads();

    {   // scatter u's into per-k sorted list
        int k = sidx[t];
        int pos = offp[k] - cnt[k] + atomicAdd(&fill[k], 1);
        list[pos] = (unsigned short)t;
    }
    __syncthreads();

    const float* xb   = x   + (size_t)b * Nn * Cn;
    float*       outb = out + (size_t)b * KEPT * Cn;
    const int wv  = t >> 6, ln = t & 63;
    const int qtr = ln >> 4;               // 4 rows per wave, 16 lanes each
    const int cq  = ln & 15;               // c4 = cq, cq+16, cq+32

    for (int pass = 0; pass < 4; ++pass) {
        int k = half * 128 + pass * 32 + wv * 4 + qtr;
        int e = offp[k], c = cnt[k], s0 = e - c;
        const float* xr = xb + (size_t)k * Cn;
        float4 a0 = *reinterpret_cast<const float4*>(xr + cq * 4);
        float4 a1 = *reinterpret_cast<const float4*>(xr + (cq + 16) * 4);
        float4 a2 = *reinterpret_cast<const float4*>(xr + (cq + 32) * 4);
        for (int i = s0; i < e; ++i) {
            const float* xs = xb + (size_t)(KEPT + list[i]) * Cn;
            float4 v0  = *reinterpret_cast<const float4*>(xs + cq * 4);
            float4 v1v = *reinterpret_cast<const float4*>(xs + (cq + 16) * 4);
            float4 v2v = *reinterpret_cast<const float4*>(xs + (cq + 32) * 4);
            a0.x += v0.x;  a0.y += v0.y;  a0.z += v0.z;  a0.w += v0.w;
            a1.x += v1v.x; a1.y += v1v.y; a1.z += v1v.z; a1.w += v1v.w;
            a2.x += v2v.x; a2.y += v2v.y; a2.z += v2v.z; a2.w += v2v.w;
        }
        float rc = 1.0f / ((float)c + 1.0f);
        float* orow = outb + (size_t)k * Cn;
        *reinterpret_cast<float4*>(orow + cq * 4) =
            make_float4(a0.x * rc, a0.y * rc, a0.z * rc, a0.w * rc);
        *reinterpret_cast<float4*>(orow + (cq + 16) * 4) =
            make_float4(a1.x * rc, a1.y * rc, a1.z * rc, a1.w * rc);
        *reinterpret_cast<float4*>(orow + (cq + 32) * 4) =
            make_float4(a2.x * rc, a2.y * rc, a2.z * rc, a2.w * rc);
    }
}

extern "C" void kernel_launch(void* const* d_in, const int* in_sizes, int n_in,
                              void* d_out, int out_size, void* d_ws, size_t ws_size,
                              hipStream_t stream) {
    const float* x = (const float*)d_in[0];
    float* out = (float*)d_out;

    char* ws = (char*)d_ws;
    float* w       = (float*)ws;                               // 512*192 f32
    float* rsw     = (float*)(ws + (size_t)512 * Cn * 4);      // 512*192 f32
    int*   dst_idx = (int*)  (ws + (size_t)2 * 512 * Cn * 4);  // 512*512 i32

    norm_kernel<<<dim3(512), dim3(768), 0, stream>>>(x, w, rsw);
    sim_kernel<<<dim3(2048), dim3(512), 0, stream>>>(x, w, rsw, dst_idx);
    merge_kernel<<<dim3(512, 2), dim3(512), 0, stream>>>(x, dst_idx, out);
}

// Round 15
// 248.646 us; speedup vs baseline: 1.7518x; 1.2240x over previous
//
#include <hip/hip_runtime.h>
#include <hip/hip_bf16.h>
#include <math.h>

#define Nn   1024
#define Cn   192
#define KEPT 256
#define COMP 512
#define UT   128
#define KT   64
#define MARGIN 4e-4f
#define WCAP 512

typedef __attribute__((ext_vector_type(8))) _Float16 half8v;
typedef __attribute__((ext_vector_type(4))) float f32x4;

__device__ __forceinline__ unsigned encf(float f) {
    unsigned u = __float_as_uint(f);
    return (u & 0x80000000u) ? ~u : (u | 0x80000000u);
}
// pack 4 floats into one u64 of 4 fp16 (RNE)
__device__ __forceinline__ unsigned long long cvt4(float m0, float m1, float m2, float m3) {
    unsigned short h0 = __builtin_bit_cast(unsigned short, (_Float16)m0);
    unsigned short h1 = __builtin_bit_cast(unsigned short, (_Float16)m1);
    unsigned short h2 = __builtin_bit_cast(unsigned short, (_Float16)m2);
    unsigned short h3 = __builtin_bit_cast(unsigned short, (_Float16)m3);
    return (unsigned long long)h0 | ((unsigned long long)h1 << 16)
         | ((unsigned long long)h2 << 32) | ((unsigned long long)h3 << 48);
}

// ---------------- Kernel A: w = 1/sumsq, rsw = rsqrt(sumsq) ----------------
__global__ __launch_bounds__(768) void norm_kernel(const float* __restrict__ x,
                                                   float* __restrict__ w,
                                                   float* __restrict__ rsw) {
    __shared__ float4 red[16][48];
    int b = blockIdx.x, t = threadIdx.x;
    int c4 = t % 48, ng = t / 48;
    const float* xb = x + (size_t)b * Nn * Cn;
    float4 s = make_float4(0.f, 0.f, 0.f, 0.f);
    for (int i = 0; i < 64; ++i) {
        float4 v = *reinterpret_cast<const float4*>(
            xb + (size_t)(ng * 64 + i) * Cn + c4 * 4);
        s.x += v.x * v.x; s.y += v.y * v.y; s.z += v.z * v.z; s.w += v.w * v.w;
    }
    red[ng][c4] = s;
    __syncthreads();
    if (t < 48) {
        float4 a = make_float4(0.f, 0.f, 0.f, 0.f);
        #pragma unroll
        for (int g = 0; g < 16; ++g) {
            float4 v = red[g][t];
            a.x += v.x; a.y += v.y; a.z += v.z; a.w += v.w;
        }
        float4 wv = make_float4(1.0f / a.x, 1.0f / a.y, 1.0f / a.z, 1.0f / a.w);
        float4 rv = make_float4(rsqrtf(a.x), rsqrtf(a.y), rsqrtf(a.z), rsqrtf(a.w));
        *reinterpret_cast<float4*>(w   + (size_t)b * Cn + t * 4) = wv;
        *reinterpret_cast<float4*>(rsw + (size_t)b * Cn + t * 4) = rv;
    }
}

// ------- Kernel B: fp16 MFMA sim + top-2 gap test + wave-parallel exact rescue -------
// ROUND-10 VERBATIM (proven ~90 µs). 1-D grid 2048, 4 u-blocks of each b share an XCD.
// Do NOT hoist A-fragments (round-14: +24 VGPR live range cost ~80 µs).
__global__ __launch_bounds__(512) void sim_kernel(const float* __restrict__ x,
                                                  const float* __restrict__ w,
                                                  const float* __restrict__ rsw,
                                                  int* __restrict__ dst_idx) {
    __shared__ __align__(16) unsigned short su_h[UT * Cn];    // 49152 B
    __shared__ __align__(16) unsigned short sk_h[KT * Cn];    // 24576 B
    __shared__ float rl[Cn];
    __shared__ float wl[Cn];
    __shared__ float rowthr[UT];
    __shared__ unsigned long long best[UT];
    __shared__ unsigned short wlist[WCAP];
    __shared__ int nc;

    const int bi   = blockIdx.x;
    const int xcd  = bi & 7;
    const int slot = bi >> 3;
    const int b    = xcd * 64 + (slot >> 2);
    const int u0   = (slot & 3) * UT;
    const int t    = threadIdx.x;
    const float* xb = x + (size_t)b * Nn * Cn;

    if (t < Cn) { rl[t] = rsw[b * Cn + t]; wl[t] = w[b * Cn + t]; }
    if (t < UT) { rowthr[t] = INFINITY; best[t] = 0ull; }
    if (t == 0) nc = 0;
    __syncthreads();

    // ---- stage su (128 unimp rows) as fp16, swizzled ----
    #pragma unroll
    for (int i = 0; i < 12; ++i) {
        int idx = t + 512 * i;
        int r = idx / 48, c4 = idx % 48;
        float4 v = *reinterpret_cast<const float4*>(
            xb + (size_t)(KEPT + u0 + r) * Cn + c4 * 4);
        unsigned long long h = cvt4(v.x * rl[c4 * 4 + 0], v.y * rl[c4 * 4 + 1],
                                    v.z * rl[c4 * 4 + 2], v.w * rl[c4 * 4 + 3]);
        int byte = r * 384 + ((c4 * 8) ^ ((r & 7) << 4));
        *reinterpret_cast<unsigned long long*>(reinterpret_cast<char*>(su_h) + byte) = h;
    }

    float4 pf[6];
    #pragma unroll
    for (int i = 0; i < 6; ++i) {
        int idx = t + 512 * i;
        int r = idx / 48, c4 = idx % 48;
        pf[i] = *reinterpret_cast<const float4*>(xb + (size_t)r * Cn + c4 * 4);
    }

    const int wv   = t >> 6;
    const int ln   = t & 63;
    const int l15  = ln & 15;
    const int hi2  = ln >> 4;
    const int akey = (l15 & 7) << 4;
    const int abase = (wv * 16 + l15) * 384;
    int bbase[4];
    #pragma unroll
    for (int j = 0; j < 4; ++j) bbase[j] = (j * 16 + l15) * 384;

    f32x4 acc[4][4];
    #pragma unroll
    for (int kt = 0; kt < 4; ++kt)
        #pragma unroll
        for (int j = 0; j < 4; ++j) acc[kt][j] = (f32x4)0.f;

    #pragma unroll
    for (int kt = 0; kt < 4; ++kt) {
        __syncthreads();
        #pragma unroll
        for (int i = 0; i < 6; ++i) {
            int idx = t + 512 * i;
            int r = idx / 48, c4 = idx % 48;
            unsigned long long h = cvt4(pf[i].x * rl[c4 * 4 + 0], pf[i].y * rl[c4 * 4 + 1],
                                        pf[i].z * rl[c4 * 4 + 2], pf[i].w * rl[c4 * 4 + 3]);
            int byte = r * 384 + ((c4 * 8) ^ ((r & 7) << 4));
            *reinterpret_cast<unsigned long long*>(reinterpret_cast<char*>(sk_h) + byte) = h;
        }
        __syncthreads();
        if (kt < 3) {
            #pragma unroll
            for (int i = 0; i < 6; ++i) {
                int idx = t + 512 * i;
                int r = idx / 48, c4 = idx % 48;
                pf[i] = *reinterpret_cast<const float4*>(
                    xb + (size_t)((kt + 1) * KT + r) * Cn + c4 * 4);
            }
        }

        #pragma unroll
        for (int ks = 0; ks < 6; ++ks) {
            int koff = (ks * 64 + hi2 * 16) ^ akey;
            half8v ah = *reinterpret_cast<const half8v*>(
                reinterpret_cast<const char*>(su_h) + abase + koff);
            #pragma unroll
            for (int j = 0; j < 4; ++j) {
                half8v bh = *reinterpret_cast<const half8v*>(
                    reinterpret_cast<const char*>(sk_h) + bbase[j] + koff);
                acc[kt][j] = __builtin_amdgcn_mfma_f32_16x16x32_f16(ah, bh, acc[kt][j], 0, 0, 0);
            }
        }
    }

    // ---- top-2 (value, argmax-with-lowest-k, 2nd value) per row ----
    float v1[4], v2[4];
    int   i1[4];
    #pragma unroll
    for (int r = 0; r < 4; ++r) { v1[r] = -INFINITY; v2[r] = -INFINITY; i1[r] = 1; }

    #pragma unroll
    for (int kt = 0; kt < 4; ++kt)
        #pragma unroll
        for (int j = 0; j < 4; ++j) {
            int k = kt * KT + j * 16 + l15;
            #pragma unroll
            for (int r = 0; r < 4; ++r) {
                float v = acc[kt][j][r];
                if (k != 0) {
                    if (v > v1[r]) { v2[r] = v1[r]; v1[r] = v; i1[r] = k; }
                    else if (v > v2[r]) v2[r] = v;
                }
            }
        }

    #pragma unroll
    for (int r = 0; r < 4; ++r) {
        #pragma unroll
        for (int off = 1; off < 16; off <<= 1) {
            float ov1 = __shfl_xor(v1[r], off);
            int   oi1 = __shfl_xor(i1[r], off);
            float ov2 = __shfl_xor(v2[r], off);
            if (ov1 > v1[r] || (ov1 == v1[r] && oi1 < i1[r])) {
                v2[r] = fmaxf(v1[r], ov2);
                v1[r] = ov1; i1[r] = oi1;
            } else {
                v2[r] = fmaxf(v2[r], ov1);
            }
        }
    }

    if (l15 == 0) {
        #pragma unroll
        for (int r = 0; r < 4; ++r) {
            int ur = wv * 16 + hi2 * 4 + r;
            if (v1[r] - v2[r] > MARGIN) dst_idx[b * COMP + u0 + ur] = i1[r];
            else rowthr[ur] = v1[r] - MARGIN;
        }
    }
    __syncthreads();

    // ---- candidate push for flagged rows ----
    #pragma unroll
    for (int kt = 0; kt < 4; ++kt)
        #pragma unroll
        for (int j = 0; j < 4; ++j) {
            int k = kt * KT + j * 16 + l15;
            if (k == 0) continue;
            #pragma unroll
            for (int r = 0; r < 4; ++r) {
                int ur = wv * 16 + hi2 * 4 + r;
                if (acc[kt][j][r] >= rowthr[ur]) {
                    int pos = atomicAdd(&nc, 1);
                    if (pos < WCAP)
                        wlist[pos] = (unsigned short)((ur << 8) | k);
                }
            }
        }
    __syncthreads();

    // ---- wave-parallel exact fp32 rescue ----
    int n = nc < WCAP ? nc : WCAP;
    for (int ci = wv; ci < n; ci += 8) {
        unsigned item = wlist[ci];
        int ur = item >> 8, k = item & 255;
        const float* xu = xb + (size_t)(KEPT + u0 + ur) * Cn;
        const float* xk = xb + (size_t)k * Cn;
        float p = 0.f;
        if (ln < 48) {
            float4 a  = *reinterpret_cast<const float4*>(xu + ln * 4);
            float4 b4 = *reinterpret_cast<const float4*>(xk + ln * 4);
            p = a.x * b4.x * wl[ln * 4 + 0] + a.y * b4.y * wl[ln * 4 + 1]
              + a.z * b4.z * wl[ln * 4 + 2] + a.w * b4.w * wl[ln * 4 + 3];
        }
        #pragma unroll
        for (int off = 32; off >= 1; off >>= 1) p += __shfl_xor(p, off);
        if (ln == 0) {
            unsigned long long e = ((unsigned long long)encf(p) << 32)
                                 | (unsigned long long)(0xFFFFFFFFu - (unsigned)k);
            atomicMax(&best[ur], e);
        }
    }
    __syncthreads();

    if (t < UT && rowthr[t] < 3.0e38f) {
        unsigned k = 0xFFFFFFFFu - (unsigned)(best[t] & 0xFFFFFFFFull);
        dst_idx[b * COMP + u0 + t] = (int)k;
    }
}

// ------- Kernel C: counting-sort gather merge, k-split 2-way, wave-shuffle scan -------
// grid (512, 2): block (b, half) gathers k in [half*128, half*128+128).
__global__ __launch_bounds__(512) void merge_kernel(const float* __restrict__ x,
                                                    const int* __restrict__ dst_idx,
                                                    float* __restrict__ out) {
    __shared__ int sidx[COMP];
    __shared__ int cnt[KEPT];
    __shared__ int offp[KEPT];    // inclusive prefix sum
    __shared__ int fill[KEPT];
    __shared__ unsigned short list[COMP];
    __shared__ int wsum[4];

    int b = blockIdx.x, half = blockIdx.y, t = threadIdx.x;

    if (t < KEPT) { cnt[t] = 0; fill[t] = 0; }
    sidx[t] = dst_idx[b * COMP + t];
    __syncthreads();
    atomicAdd(&cnt[sidx[t]], 1);
    __syncthreads();

    // wave-shuffle inclusive scan over 256 bins (waves 0..3)
    int v = 0;
    if (t < KEPT) {
        v = cnt[t];
        int lane = t & 63;
        #pragma unroll
        for (int off = 1; off < 64; off <<= 1) {
            int u = __shfl_up(v, off);
            if (lane >= off) v += u;
        }
        if (lane == 63) wsum[t >> 6] = v;
    }
    __syncthreads();
    if (t < KEPT) {
        int wid = t >> 6;
        if (wid > 0) v += wsum[0];
        if (wid > 1) v += wsum[1];
        if (wid > 2) v += wsum[2];
        offp[t] = v;
    }
    __syncthreads();

    {   // scatter u's into per-k sorted list
        int k = sidx[t];
        int pos = offp[k] - cnt[k] + atomicAdd(&fill[k], 1);
        list[pos] = (unsigned short)t;
    }
    __syncthreads();

    const float* xb   = x   + (size_t)b * Nn * Cn;
    float*       outb = out + (size_t)b * KEPT * Cn;
    const int wv  = t >> 6, ln = t & 63;
    const int qtr = ln >> 4;               // 4 rows per wave, 16 lanes each
    const int cq  = ln & 15;               // c4 = cq, cq+16, cq+32

    for (int pass = 0; pass < 4; ++pass) {
        int k = half * 128 + pass * 32 + wv * 4 + qtr;
        int e = offp[k], c = cnt[k], s0 = e - c;
        const float* xr = xb + (size_t)k * Cn;
        float4 a0 = *reinterpret_cast<const float4*>(xr + cq * 4);
        float4 a1 = *reinterpret_cast<const float4*>(xr + (cq + 16) * 4);
        float4 a2 = *reinterpret_cast<const float4*>(xr + (cq + 32) * 4);
        for (int i = s0; i < e; ++i) {
            const float* xs = xb + (size_t)(KEPT + list[i]) * Cn;
            float4 v0  = *reinterpret_cast<const float4*>(xs + cq * 4);
            float4 v1v = *reinterpret_cast<const float4*>(xs + (cq + 16) * 4);
            float4 v2v = *reinterpret_cast<const float4*>(xs + (cq + 32) * 4);
            a0.x += v0.x;  a0.y += v0.y;  a0.z += v0.z;  a0.w += v0.w;
            a1.x += v1v.x; a1.y += v1v.y; a1.z += v1v.z; a1.w += v1v.w;
            a2.x += v2v.x; a2.y += v2v.y; a2.z += v2v.z; a2.w += v2v.w;
        }
        float rc = 1.0f / ((float)c + 1.0f);
        float* orow = outb + (size_t)k * Cn;
        *reinterpret_cast<float4*>(orow + cq * 4) =
            make_float4(a0.x * rc, a0.y * rc, a0.z * rc, a0.w * rc);
        *reinterpret_cast<float4*>(orow + (cq + 16) * 4) =
            make_float4(a1.x * rc, a1.y * rc, a1.z * rc, a1.w * rc);
        *reinterpret_cast<float4*>(orow + (cq + 32) * 4) =
            make_float4(a2.x * rc, a2.y * rc, a2.z * rc, a2.w * rc);
    }
}

extern "C" void kernel_launch(void* const* d_in, const int* in_sizes, int n_in,
                              void* d_out, int out_size, void* d_ws, size_t ws_size,
                              hipStream_t stream) {
    const float* x = (const float*)d_in[0];
    float* out = (float*)d_out;

    char* ws = (char*)d_ws;
    float* w       = (float*)ws;                               // 512*192 f32
    float* rsw     = (float*)(ws + (size_t)512 * Cn * 4);      // 512*192 f32
    int*   dst_idx = (int*)  (ws + (size_t)2 * 512 * Cn * 4);  // 512*512 i32

    norm_kernel<<<dim3(512), dim3(768), 0, stream>>>(x, w, rsw);
    sim_kernel<<<dim3(2048), dim3(512), 0, stream>>>(x, w, rsw, dst_idx);
    merge_kernel<<<dim3(512, 2), dim3(512), 0, stream>>>(x, dst_idx, out);
}